// Round 10
// baseline (378.224 us; speedup 1.0000x reference)
//
#include <hip/hip_runtime.h>
#include <hip/hip_bf16.h>

// Problem constants (B=2, D=64, H=W=96)
constexpr int B_    = 2;
constexpr int N_    = 9216;      // 96*96
constexpr int ITERS = 4;

constexpr int MTQ     = 128;          // queries per workgroup (m-split: 32/wave)
constexpr int MBF     = N_ / MTQ;     // 72 m-blocks
constexpr int KS      = 4;            // key-split factor
constexpr int KEYS_WG = N_ / KS;      // 2304 keys per workgroup
constexpr int KT      = 64;           // keys per staged tile
constexpr int KTILES  = KEYS_WG / KT; // 36 tiles
constexpr int NWG     = B_ * MBF * KS;// 576 flash workgroups — all resident
constexpr int PB      = 144;          // prep n-blocks of 64
constexpr int CGRID   = B_ * (N_ / 32); // 576 combine workgroups

constexpr float STEP = 0.5f;
constexpr float C2   = 0.43280851226668905f;  // KBW * log2(e)

using short8   = __attribute__((ext_vector_type(8))) short;
using float16v = __attribute__((ext_vector_type(16))) float;
typedef __attribute__((ext_vector_type(4))) unsigned uint4v;
typedef __attribute__((ext_vector_type(2))) __bf16 bf16x2;

__device__ __forceinline__ unsigned short f2bf(float f) {
  union { float f; unsigned u; } v; v.f = f;
  unsigned u = v.u;
  unsigned r = (u + 0x7fffu + ((u >> 16) & 1u)) >> 16;   // RNE
  return (unsigned short)r;
}

#if __has_builtin(__builtin_amdgcn_cvt_pk_bf16_f32)
__device__ __forceinline__ unsigned pk2bf(float a, float b) {
  bf16x2 r = __builtin_amdgcn_cvt_pk_bf16_f32(a, b);   // low <- a, high <- b, RNE
  union { bf16x2 h; unsigned u; } v; v.h = r; return v.u;
}
#else
__device__ __forceinline__ unsigned pk2bf(float a, float b) {
  return (unsigned)f2bf(a) | ((unsigned)f2bf(b) << 16);
}
#endif

// cs += lo(u) + hi(u) where u is a packed bf16 pair — 1 instr via dot2.
__device__ __forceinline__ float csum2(unsigned u, float cs) {
#if __has_builtin(__builtin_amdgcn_fdot2_f32_bf16)
  union { unsigned x; bf16x2 h; } a, o;
  a.x = u; o.x = 0x3f803f80u;                          // (1.0, 1.0) bf16
  return __builtin_amdgcn_fdot2_f32_bf16(a.h, o.h, cs, false);
#else
  union { unsigned u; float f; } lo, hi;
  lo.u = u << 16; hi.u = u & 0xffff0000u;
  return cs + lo.f + hi.f;
#endif
}

// Force a 128-bit fragment to be materialized in VGPRs at this program point.
// Defeats the compiler's (legal) sinking of ds_reads across __syncthreads —
// R15 lesson: without this, "register-carried" PV operands silently became
// LDS reads at next-interval entry (VGPR_Count 64 proved it).
__device__ __forceinline__ void keep8(short8& v) {
  asm volatile("" : "+v"(reinterpret_cast<uint4v&>(v)));
}

// Async global->LDS DMA, 16 B/lane; lds_base wave-uniform, lane i -> base+16i.
__device__ __forceinline__ void dma16(const unsigned short* g,
                                      unsigned short* lds_base, int lane) {
#if __has_builtin(__builtin_amdgcn_global_load_lds)
  __builtin_amdgcn_global_load_lds(
      (const __attribute__((address_space(1))) unsigned int*)g,
      (__attribute__((address_space(3))) unsigned int*)lds_base, 16, 0, 0);
#else
  *(int4*)((char*)lds_base + lane * 16) = *(const int4*)g;
#endif
}

// ---------------------------------------------------------------------------
// prep: x_in (fp32 [b][d][n]) -> out slice 0 (copy), Xbf bf16 [b][d][n],
//       XT bf16 [b][n][d] (LDS transpose)
// ---------------------------------------------------------------------------
__global__ void prep_kernel(const float* __restrict__ xin, float* __restrict__ out,
                            unsigned short* __restrict__ XT,
                            unsigned short* __restrict__ Xbf)
{
  const int bx = blockIdx.x;
  const int nb = bx % PB, b = bx / PB;
  const int n0 = nb * 64;
  const int tid = threadIdx.x;
  __shared__ float tile[64 * 65];

  #pragma unroll
  for (int r = 0; r < 16; ++r) {
    int idx = r * 256 + tid;
    int d = idx >> 6, j = idx & 63;
    float v = xin[((size_t)b * 64 + d) * N_ + n0 + j];
    out[(((size_t)b * 5 + 0) * 64 + d) * N_ + n0 + j] = v;
    Xbf[((size_t)b * 64 + d) * N_ + n0 + j] = f2bf(v);
    tile[d * 65 + j] = v;
  }
  __syncthreads();
  #pragma unroll
  for (int r = 0; r < 16; ++r) {
    int idx = r * 256 + tid;
    int nl = idx >> 6, d = idx & 63;
    XT[((size_t)b * N_ + n0 + nl) * 64 + d] = f2bf(tile[d * 65 + nl]);
  }
}

// ---------------------------------------------------------------------------
// flash (R16): R15's register-resident-PV, FORCED. R15's VGPR_Count=64
// proved the compiler sank BREAD's ds_reads across the barrier (legal: buf
// stays valid through interval t+1), reverting to LDS-read PV — so the
// hypothesis never ran. Fix: keep8() asm pins on every carried B-fragment
// BEFORE the barrier (ds_read must complete into VGPRs at that point), and
// s_setprio(1) around the now-genuinely-register-only PV cluster (T5's
// role-diversity precondition is now real).
// Expected signature that the carry is real: VGPR_Count ~140-160 (vs 64).
// Interval t: stage(t+1) -> PV(t-1) [pure-register MFMAs at entry] ->
//             QK(t) [af reads fly under PV] -> exp/pack -> BREAD(t)+pin ->
//             barrier.
// Geometry: R8 exact (KS=4, 576 blocks single-round @3/CU, dbuf 32 KiB,
// bounds(256,3) VGPR cap 170). σ-trick (R6) unchanged; queries pre-scaled
// by C2 -> w = exp2(S). Spill watch: FETCH_SIZE must stay ~8.1-8.5 MB.
// ---------------------------------------------------------------------------
__global__ void __launch_bounds__(256, 3) flash_kernel(
    const unsigned short* __restrict__ XT,
    const unsigned short* __restrict__ Xbf,
    float* __restrict__ pacc, float* __restrict__ pcs)
{
  const int bx   = blockIdx.x;
  const int ks   = bx & 3;
  const int mb   = (bx >> 2) % MBF;
  const int b    = bx / (MBF * KS);
  const int tid  = threadIdx.x;
  const int wave = tid >> 6, lane = tid & 63;
  const int c = lane & 31, h = lane >> 5;
  const int cp = (c & 0x13) | ((c & 4) << 1) | ((c & 8) >> 1);  // swap bits 2,3
  const int m0 = mb * MTQ;
  const int bpaddr = (lane ^ 32) << 2;      // ds_bpermute byte index (epilogue)

  const unsigned short* XTb = XT  + (size_t)b * N_ * 64;
  const unsigned short* Xb  = Xbf + (size_t)b * 64 * N_;

  __shared__ __align__(16) unsigned short sXT[2][KT * 64];  // [key][d]  8KiB x2
  __shared__ __align__(16) unsigned short sXB[2][64 * KT];  // [d][n]    8KiB x2

  // DMA lane coords: one dma16 covers 8 rows x 8 chunks; row&7 == rr, so the
  // write-side swizzle chunk gc = sc ^ rr is LANE-CONSTANT.
  const int rr = lane >> 3, sc = lane & 7;
  const int gc = sc ^ rr;

  const int n0g0 = ks * KEYS_WG;

  // per-lane global DMA pointers (tile 0); advance by constants per tile.
  const unsigned short* xtp  = XTb + (size_t)(n0g0 + wave * 16 + rr) * 64 + gc * 8;
  const unsigned short* xbp0 = Xb  + (size_t)(wave * 16 + rr) * N_ + n0g0 + gc * 8;
  const unsigned short* xbp1 = xbp0 + (size_t)8 * N_;

  auto stage = [&](int buf, const unsigned short* xt_,
                   const unsigned short* xb0_, const unsigned short* xb1_) {
    unsigned short* lt = &sXT[buf][wave * 16 * 64];   // 16 key rows / wave
    unsigned short* lb = &sXB[buf][wave * 16 * 64];   // 16 d rows / wave
    dma16(xt_,       lt,       lane);
    dma16(xt_ + 512, lt + 512, lane);
    dma16(xb0_,      lb,       lane);
    dma16(xb1_,      lb + 512, lane);
  };

  stage(0, xtp, xbp0, xbp1);                 // prologue DMA flies under qf setup
  xtp += KT * 64; xbp0 += KT; xbp1 += KT;

  // wave's resident query fragments (B-operand), pre-scaled by C2
  short8 qf[4];
  #pragma unroll
  for (int k = 0; k < 4; ++k) {
    short8 raw = *(const short8*)(XTb +
        (size_t)(m0 + wave * 32 + c) * 64 + k * 16 + h * 8);
    unsigned o[4];
    const unsigned* rw = (const unsigned*)&raw;
    #pragma unroll
    for (int p4 = 0; p4 < 4; ++p4) {
      union { unsigned u; float f; } lo, hi;
      lo.u = rw[p4] << 16; hi.u = rw[p4] & 0xffff0000u;
      o[p4] = pk2bf(lo.f * C2, hi.f * C2);
    }
    qf[k] = *(const short8*)o;
  }

  // persistent per-lane LDS read bases (buf 0); buf/s/dt -> offset immediates
  const int e = cp & 7;
  const unsigned short* afb[4];
  #pragma unroll
  for (int k = 0; k < 4; ++k)
    afb[k] = &sXT[0][cp * 64 + ((2 * k + h) ^ e) * 8];
  const int ec = c & 7;
  const unsigned short* bfb0[2], * bfb1[2];   // [s], k2=0 / k2=1
  #pragma unroll
  for (int s = 0; s < 2; ++s) {
    bfb0[s] = &sXB[0][c * 64 + ((4 * s +     h) ^ ec) * 8];
    bfb1[s] = &sXB[0][c * 64 + ((4 * s + 2 + h) ^ ec) * 8];
  }

  float16v zv;
  #pragma unroll
  for (int p = 0; p < 16; ++p) zv[p] = 0.f;
  float16v acc[2];
  acc[0] = zv; acc[1] = zv;
  float cs0 = 0.f, cs1 = 0.f;

  // cross-barrier carried state: W of previous tile + its X b-frags
  unsigned qwp[2][8];              // [s][g]  packed bf16 weights
  short8 b20c[2][2], b21c[2][2];   // [s][dt] X fragments — PINNED in VGPRs

  // ---- QK + exp for tile `buf` -> qwp, cs (af ds_reads from buf) ----------
  auto QKEXP = [&](int buf) {
    #pragma unroll
    for (int s = 0; s < 2; ++s) {
      short8 af[4];
      #pragma unroll
      for (int k = 0; k < 4; ++k)
        af[k] = *(const short8*)(afb[k] + buf * 4096 + s * 2048);
      float16v S = zv;
      #pragma unroll
      for (int k = 0; k < 4; ++k)
        S = __builtin_amdgcn_mfma_f32_32x32x16_bf16(af[k], qf[k], S, 0, 0, 0);
      #pragma unroll
      for (int g = 0; g < 8; ++g) {
        float w0 = __builtin_amdgcn_exp2f(S[2 * g]);
        float w1 = __builtin_amdgcn_exp2f(S[2 * g + 1]);
        unsigned u = pk2bf(w0, w1);
        qwp[s][g] = u;
        if (s) cs1 = csum2(u, cs1); else cs0 = csum2(u, cs0);
      }
    }
  };
  // ---- load b-frags of tile `buf` into registers and PIN them -------------
  auto BREAD = [&](int buf) {
    #pragma unroll
    for (int s = 0; s < 2; ++s) {
      b20c[s][0] = *(const short8*)(bfb0[s] + buf * 4096);
      b20c[s][1] = *(const short8*)(bfb0[s] + buf * 4096 + 2048);
      b21c[s][0] = *(const short8*)(bfb1[s] + buf * 4096);
      b21c[s][1] = *(const short8*)(bfb1[s] + buf * 4096 + 2048);
    }
    #pragma unroll
    for (int s = 0; s < 2; ++s) {
      keep8(b20c[s][0]); keep8(b20c[s][1]);
      keep8(b21c[s][0]); keep8(b21c[s][1]);
    }
  };
  // ---- PV of previous tile: PURE REGISTER MFMAs (qwp x pinned bcar) -------
  auto PV = [&]() {
    __builtin_amdgcn_s_setprio(1);
    #pragma unroll
    for (int s = 0; s < 2; ++s) {
      union { unsigned d[4]; short8 s8; } a20, a21;
      #pragma unroll
      for (int j = 0; j < 4; ++j) { a20.d[j] = qwp[s][j]; a21.d[j] = qwp[s][4 + j]; }
      acc[0] = __builtin_amdgcn_mfma_f32_32x32x16_bf16(a20.s8, b20c[s][0], acc[0], 0, 0, 0);
      acc[1] = __builtin_amdgcn_mfma_f32_32x32x16_bf16(a20.s8, b20c[s][1], acc[1], 0, 0, 0);
      acc[0] = __builtin_amdgcn_mfma_f32_32x32x16_bf16(a21.s8, b21c[s][0], acc[0], 0, 0, 0);
      acc[1] = __builtin_amdgcn_mfma_f32_32x32x16_bf16(a21.s8, b21c[s][1], acc[1], 0, 0, 0);
    }
    __builtin_amdgcn_s_setprio(0);
  };

  __syncthreads();               // buf0 ready (drains prologue DMA + qf loads)

  // prologue interval (tile 0): no PV yet
  stage(1, xtp, xbp0, xbp1);
  xtp += KT * 64; xbp0 += KT; xbp1 += KT;
  QKEXP(0);
  BREAD(0);
  __syncthreads();               // buf1 ready; all waves done reading buf0

  #pragma unroll 2
  for (int t = 1; t < KTILES; ++t) {
    const int buf = t & 1;       // constexpr after unroll-2
    if (t + 1 < KTILES) {        // stage(t+1) overwrites buf^1 (safe: barrier)
      stage(buf ^ 1, xtp, xbp0, xbp1);
      xtp += KT * 64; xbp0 += KT; xbp1 += KT;
    }
    PV();                        // tile t-1: zero memory deps, issues at entry
    QKEXP(buf);                  // tile t: af reads fly under PV
    BREAD(buf);                  // tile t b-frags -> regs, pinned pre-barrier
    __syncthreads();
  }

  PV();                          // final PV (tile KTILES-1)
  float cs = cs0 + cs1;

  // -------- epilogue: wave-disjoint outputs, direct global writes ----------
  union { float f; int i; } cu; cu.f = cs;
  cu.i = __builtin_amdgcn_ds_bpermute(bpaddr, cu.i);
  float cst = cs + cu.f;                     // both h-halves hold the total
  if (h == 0) pcs[(size_t)bx * 128 + wave * 32 + c] = cst;

  float* pw = pacc + (size_t)bx * (MTQ * 64);
  #pragma unroll
  for (int dt = 0; dt < 2; ++dt)
    #pragma unroll
    for (int p = 0; p < 16; ++p) {
      int m = wave * 32 + (p & 3) + 8 * (p >> 2) + 4 * h;
      pw[m * 64 + dt * 32 + c] = acc[dt][p];
    }
}

// ---------------------------------------------------------------------------
// combine: sum KS partials, normalize, blend with x_cur (= out slice t),
// write out slice t+1 + next iteration's Xbf / XT (bf16).
// 576 blocks, each owns a 32-query x 64-d slab of a 128-q flash block.
// ---------------------------------------------------------------------------
__global__ void combine_kernel(const float* __restrict__ pacc,
                               const float* __restrict__ pcs,
                               float* __restrict__ out,
                               unsigned short* __restrict__ XT,
                               unsigned short* __restrict__ Xbf, int t)
{
  const int bx  = blockIdx.x;
  const int q32 = bx % 288, b = bx / 288;
  const int m0  = q32 * 32;
  const int base = (b * MBF + (q32 >> 2)) * KS;  // flash block row (128 q)
  const int poff = (q32 & 3) * 2048;             // float offset into 128x64 blk
  const int coff = (q32 & 3) * 32;
  const int tid = threadIdx.x;
  __shared__ float accs[32 * 65];
  __shared__ float cstl[32];

  #pragma unroll
  for (int r = 0; r < 2; ++r) {
    int i4 = r * 256 + tid;                      // float4 idx within 32x64
    float4 s = make_float4(0.f, 0.f, 0.f, 0.f);
    #pragma unroll
    for (int k = 0; k < KS; ++k) {
      const float4* p = (const float4*)(pacc + (size_t)(base + k) * 8192 + poff);
      float4 v = p[i4];
      s.x += v.x; s.y += v.y; s.z += v.z; s.w += v.w;
    }
    int m = i4 >> 4, d0 = (i4 & 15) * 4;
    accs[m * 65 + d0 + 0] = s.x;
    accs[m * 65 + d0 + 1] = s.y;
    accs[m * 65 + d0 + 2] = s.z;
    accs[m * 65 + d0 + 3] = s.w;
  }
  if (tid < 32) {
    float cv = 0.f;
    #pragma unroll
    for (int k = 0; k < KS; ++k) cv += pcs[(size_t)(base + k) * 128 + coff + tid];
    cstl[tid] = cv;
  }
  __syncthreads();

  #pragma unroll
  for (int r = 0; r < 4; ++r) {
    int idx = r * 256 + tid;                    // 0..1023
    int ml = (idx & 15) * 2, d = idx >> 4;      // m fastest -> coalesced n
    float a0 = accs[ml * 65 + d], a1 = accs[(ml + 1) * 65 + d];
    size_t obase = (((size_t)b * 5 + t) * 64 + d) * N_ + m0 + ml;
    float2 xc = *(const float2*)(out + obase);
    float v0 = STEP * (a0 / cstl[ml])     + (1.f - STEP) * xc.x;
    float v1 = STEP * (a1 / cstl[ml + 1]) + (1.f - STEP) * xc.y;
    *(float2*)(out + obase + (size_t)64 * N_) = make_float2(v0, v1);  // slice t+1
    *(unsigned*)(Xbf + ((size_t)b * 64 + d) * N_ + m0 + ml) = pk2bf(v0, v1);
    accs[ml * 65 + d] = v0; accs[(ml + 1) * 65 + d] = v1;  // for transpose
  }
  __syncthreads();

  #pragma unroll
  for (int r = 0; r < 4; ++r) {
    int idx = r * 256 + tid;
    int m = idx >> 5, d = (idx & 31) * 2;       // d fastest -> coalesced XT row
    *(unsigned*)(XT + ((size_t)b * N_ + m0 + m) * 64 + d)
        = pk2bf(accs[m * 65 + d], accs[m * 65 + d + 1]);
  }
}

// ---------------------------------------------------------------------------
extern "C" void kernel_launch(void* const* d_in, const int* in_sizes, int n_in,
                              void* d_out, int out_size, void* d_ws, size_t ws_size,
                              hipStream_t stream)
{
  (void)in_sizes; (void)n_in; (void)out_size; (void)ws_size;
  const float* xin = (const float*)d_in[0];
  float* out = (float*)d_out;
  char* ws = (char*)d_ws;

  // workspace layout (23,887,872 B total — identical footprint to R1-R8):
  unsigned short* XT  = (unsigned short*)(ws);             //  2,359,296 B
  unsigned short* Xbf = (unsigned short*)(ws +  2359296);  //  2,359,296 B
  float*          pacc = (float*)(ws +  4718592);          // 18,874,368 B (576*8192*4)
  float*          pcs  = (float*)(ws + 23592960);          //    294,912 B (576*128*4)

  prep_kernel<<<B_ * PB, 256, 0, stream>>>(xin, out, XT, Xbf);
  for (int t = 0; t < ITERS; ++t) {
    flash_kernel<<<NWG, 256, 0, stream>>>(XT, Xbf, pacc, pcs);
    combine_kernel<<<CGRID, 256, 0, stream>>>(pacc, pcs, out, XT, Xbf, t);
  }
}

// Round 12
// 342.906 us; speedup vs baseline: 1.1030x; 1.1030x over previous
//
#include <hip/hip_runtime.h>
#include <hip/hip_bf16.h>

// Problem constants (B=2, D=64, H=W=96)
constexpr int B_    = 2;
constexpr int N_    = 9216;      // 96*96
constexpr int ITERS = 4;

constexpr int MTQ     = 128;          // queries per workgroup (m-split: 32/wave)
constexpr int MBF     = N_ / MTQ;     // 72 m-blocks
constexpr int KS      = 3;            // key-split factor
constexpr int KEYS_WG = N_ / KS;      // 3072 keys per workgroup
constexpr int KT      = 128;          // keys per staged tile (BIG: fewer barriers)
constexpr int KTILES  = KEYS_WG / KT; // 24 tiles -> 24 barriers (was 36)
constexpr int NWG     = B_ * MBF * KS;// 432 flash workgroups — ALL resident @2/CU
constexpr int PB      = 144;          // prep n-blocks of 64
constexpr int CGRID   = B_ * (N_ / 32); // 576 combine workgroups

constexpr float STEP = 0.5f;
constexpr float C2   = 0.43280851226668905f;  // KBW * log2(e)

using short8   = __attribute__((ext_vector_type(8))) short;
using float16v = __attribute__((ext_vector_type(16))) float;
typedef __attribute__((ext_vector_type(2))) __bf16 bf16x2;

__device__ __forceinline__ unsigned short f2bf(float f) {
  union { float f; unsigned u; } v; v.f = f;
  unsigned u = v.u;
  unsigned r = (u + 0x7fffu + ((u >> 16) & 1u)) >> 16;   // RNE
  return (unsigned short)r;
}

#if __has_builtin(__builtin_amdgcn_cvt_pk_bf16_f32)
__device__ __forceinline__ unsigned pk2bf(float a, float b) {
  bf16x2 r = __builtin_amdgcn_cvt_pk_bf16_f32(a, b);   // low <- a, high <- b, RNE
  union { bf16x2 h; unsigned u; } v; v.h = r; return v.u;
}
#else
__device__ __forceinline__ unsigned pk2bf(float a, float b) {
  return (unsigned)f2bf(a) | ((unsigned)f2bf(b) << 16);
}
#endif

// cs += lo(u) + hi(u) where u is a packed bf16 pair — 1 instr via dot2.
__device__ __forceinline__ float csum2(unsigned u, float cs) {
#if __has_builtin(__builtin_amdgcn_fdot2_f32_bf16)
  union { unsigned x; bf16x2 h; } a, o;
  a.x = u; o.x = 0x3f803f80u;                          // (1.0, 1.0) bf16
  return __builtin_amdgcn_fdot2_f32_bf16(a.h, o.h, cs, false);
#else
  union { unsigned u; float f; } lo, hi;
  lo.u = u << 16; hi.u = u & 0xffff0000u;
  return cs + lo.f + hi.f;
#endif
}

// Async global->LDS DMA, 16 B/lane; lds_base wave-uniform, lane i -> base+16i.
__device__ __forceinline__ void dma16(const unsigned short* g,
                                      unsigned short* lds_base, int lane) {
#if __has_builtin(__builtin_amdgcn_global_load_lds)
  __builtin_amdgcn_global_load_lds(
      (const __attribute__((address_space(1))) unsigned int*)g,
      (__attribute__((address_space(3))) unsigned int*)lds_base, 16, 0, 0);
#else
  *(int4*)((char*)lds_base + lane * 16) = *(const int4*)g;
#endif
}

// ---------------------------------------------------------------------------
// prep: x_in (fp32 [b][d][n]) -> out slice 0 (copy), Xbf bf16 [b][d][n],
//       XT bf16 [b][n][d] (LDS transpose)
// ---------------------------------------------------------------------------
__global__ void prep_kernel(const float* __restrict__ xin, float* __restrict__ out,
                            unsigned short* __restrict__ XT,
                            unsigned short* __restrict__ Xbf)
{
  const int bx = blockIdx.x;
  const int nb = bx % PB, b = bx / PB;
  const int n0 = nb * 64;
  const int tid = threadIdx.x;
  __shared__ float tile[64 * 65];

  #pragma unroll
  for (int r = 0; r < 16; ++r) {
    int idx = r * 256 + tid;
    int d = idx >> 6, j = idx & 63;
    float v = xin[((size_t)b * 64 + d) * N_ + n0 + j];
    out[(((size_t)b * 5 + 0) * 64 + d) * N_ + n0 + j] = v;
    Xbf[((size_t)b * 64 + d) * N_ + n0 + j] = f2bf(v);
    tile[d * 65 + j] = v;
  }
  __syncthreads();
  #pragma unroll
  for (int r = 0; r < 16; ++r) {
    int idx = r * 256 + tid;
    int nl = idx >> 6, d = idx & 63;
    XT[((size_t)b * N_ + n0 + nl) * 64 + d] = f2bf(tile[d * 65 + nl]);
  }
}

// ---------------------------------------------------------------------------
// flash (R17, resubmitted after infra failure): MINIMIZE barriers x blocks/CU
// — the product every prior probe left unchanged.
//
// Unified model fitting ALL of R6-R16: wall = barriers x blocks/CU x ~2.3k cy,
// nearly independent of tile size / work content / LDS reads / occupancy /
// sync flavor. (R8: 36x2.25=81 -> 77us; R12: 18x4.5=81 -> 75us; R6: 36x2.25
// -> 79us; R7 round-1: 18x2=36 -> ~41.5us. Every "null" changed work per
// interval, never the product.)
// This round: KT=128 (24 barriers, KS=3) at FULL residency:
//   LDS = 2 x (16K sXT + 16K sXB) = 64 KiB -> cap 2/CU; NWG=432 <= 512 ->
//   all blocks resident, one round (R7's sole failure fixed).
//   Product = 24 x 2 = 48  ->  predicted flash ~46-58 us (was 75).
// Skeleton = R8 exactly (best measured): prefetch-before-compute, ONE
// __syncthreads per tile, zero per-tile address VALU, m-split waves with
// wave-disjoint outputs. s runs 0..3 (4 key-subtiles of 32 per tile).
// sXB rows now 16 chunks: dma swizzle needs even/odd-j pointer pairs
// (row&7 gains bit 2 across the 4-row dma16 batches; audited: gcB0/gcB1
// match the read-side ^(c&7) for every row).
// σ-trick (validated R6) unchanged; queries pre-scaled by C2 -> w=exp2(S).
// bounds(256,2): VGPR cap ~256 at 2 waves/SIMD — no forced spill (R9
// lesson); LDS is the residency limiter by design.
// ---------------------------------------------------------------------------
__global__ void __launch_bounds__(256, 2) flash_kernel(
    const unsigned short* __restrict__ XT,
    const unsigned short* __restrict__ Xbf,
    float* __restrict__ pacc, float* __restrict__ pcs)
{
  const int bx   = blockIdx.x;
  const int ks   = bx % KS;
  const int mb   = (bx / KS) % MBF;
  const int b    = bx / (MBF * KS);
  const int tid  = threadIdx.x;
  const int wave = tid >> 6, lane = tid & 63;
  const int c = lane & 31, h = lane >> 5;
  const int cp = (c & 0x13) | ((c & 4) << 1) | ((c & 8) >> 1);  // swap bits 2,3
  const int m0 = mb * MTQ;
  const int bpaddr = (lane ^ 32) << 2;      // ds_bpermute byte index (epilogue)

  const unsigned short* XTb = XT  + (size_t)b * N_ * 64;
  const unsigned short* Xb  = Xbf + (size_t)b * 64 * N_;

  __shared__ __align__(16) unsigned short sXT[2][KT * 64];   // [key][d] 16KiB x2
  __shared__ __align__(16) unsigned short sXB[2][64 * KT];   // [d][n]   16KiB x2

  // ---- DMA lane coords ----------------------------------------------------
  // sXT: rows of 64 elem = 8 chunks; one dma16 = 8 rows x 8 chunks.
  const int rr  = lane >> 3, sc = lane & 7;
  const int gcT = sc ^ rr;                      // row&7 == rr in every batch
  // sXB: rows of 128 elem = 16 chunks; one dma16 = 4 rows x 16 chunks.
  // row = wave*16 + j*4 + rr4 -> row&7 = (j&1)*4 + rr4: two lane-constant
  // swizzles (j even / j odd).
  const int rr4 = lane >> 4, sc16 = lane & 15;
  const int gcB0 = sc16 ^ rr4;                  // j even
  const int gcB1 = sc16 ^ (4 + rr4);            // j odd

  const int n0g0 = ks * KEYS_WG;

  // per-lane global DMA pointers (tile 0); advance by constants per tile.
  const unsigned short* xtp  = XTb + (size_t)(n0g0 + wave * 32 + rr) * 64 + gcT * 8;
  const unsigned short* xbpA = Xb  + (size_t)(wave * 16 + rr4) * N_ + n0g0 + gcB0 * 8;
  const unsigned short* xbpB = Xb  + (size_t)(wave * 16 + rr4) * N_ + n0g0 + gcB1 * 8;

  auto stage = [&](int buf, const unsigned short* xt_,
                   const unsigned short* xbA_, const unsigned short* xbB_) {
    unsigned short* lt = &sXT[buf][wave * 32 * 64];    // 32 key rows / wave
    unsigned short* lb = &sXB[buf][wave * 16 * 128];   // 16 d rows / wave
    dma16(xt_,        lt,        lane);                // keys w*32 + 0..7
    dma16(xt_ +  512, lt +  512, lane);                // + 8..15
    dma16(xt_ + 1024, lt + 1024, lane);                // +16..23
    dma16(xt_ + 1536, lt + 1536, lane);                // +24..31
    dma16(xbA_,                    lb,        lane);   // d w*16 + 0..3
    dma16(xbB_ + (size_t) 4 * N_,  lb +  512, lane);   // + 4..7
    dma16(xbA_ + (size_t) 8 * N_,  lb + 1024, lane);   // + 8..11
    dma16(xbB_ + (size_t)12 * N_,  lb + 1536, lane);   // +12..15
  };

  stage(0, xtp, xbpA, xbpB);                 // prologue DMA flies under qf setup
  xtp += KT * 64; xbpA += KT; xbpB += KT;

  // wave's resident query fragments (B-operand), pre-scaled by C2
  short8 qf[4];
  #pragma unroll
  for (int k = 0; k < 4; ++k) {
    short8 raw = *(const short8*)(XTb +
        (size_t)(m0 + wave * 32 + c) * 64 + k * 16 + h * 8);
    unsigned o[4];
    const unsigned* rw = (const unsigned*)&raw;
    #pragma unroll
    for (int p4 = 0; p4 < 4; ++p4) {
      union { unsigned u; float f; } lo, hi;
      lo.u = rw[p4] << 16; hi.u = rw[p4] & 0xffff0000u;
      o[p4] = pk2bf(lo.f * C2, hi.f * C2);
    }
    qf[k] = *(const short8*)o;
  }

  // persistent per-lane LDS read bases (buf 0); buf/s/dt -> offset immediates
  // af: row = s*32 + cp  -> base at cp, + s*32*64 elem (s imm), + buf 16KiB.
  const int e = cp & 7;
  const unsigned short* afb[4];
  #pragma unroll
  for (int k = 0; k < 4; ++k)
    afb[k] = &sXT[0][cp * 64 + ((2 * k + h) ^ e) * 8];
  // b: row = dt*32 + c (stride 128), chunk = (4s + 2k2 + h) ^ (c&7).
  const int ec = c & 7;
  const unsigned short* bfb0[4], * bfb1[4];   // [s], k2=0 / k2=1
  #pragma unroll
  for (int s = 0; s < 4; ++s) {
    bfb0[s] = &sXB[0][c * 128 + ((4 * s +     h) ^ ec) * 8];
    bfb1[s] = &sXB[0][c * 128 + ((4 * s + 2 + h) ^ ec) * 8];
  }

  float16v zv;
  #pragma unroll
  for (int p = 0; p < 16; ++p) zv[p] = 0.f;
  float16v acc[2];
  acc[0] = zv; acc[1] = zv;
  float cs0 = 0.f, cs1 = 0.f;

  __syncthreads();               // buf0 ready (drains prologue DMA + qf loads)

  #pragma unroll 2
  for (int t = 0; t < KTILES; ++t) {
    const int buf = t & 1;       // constexpr after unroll-2
    if (t + 1 < KTILES) {        // prefetch next tile FIRST (overlaps compute)
      stage(buf ^ 1, xtp, xbpA, xbpB);
      xtp += KT * 64; xbpA += KT; xbpB += KT;
    }

    #pragma unroll
    for (int s = 0; s < 4; ++s) {           // 4 key subtiles of 32
      // A-frags (keys, σ-permuted rows): sXT[buf][(s*32+cp)][chunk]
      short8 af[4];
      #pragma unroll
      for (int k = 0; k < 4; ++k)
        af[k] = *(const short8*)(afb[k] + buf * 8192 + s * 2048);

      float16v S = zv;
      #pragma unroll
      for (int k = 0; k < 4; ++k)
        S = __builtin_amdgcn_mfma_f32_32x32x16_bf16(af[k], qf[k], S, 0, 0, 0);

      // exp2 + packed bf16; colsum from the ROUNDED weights (dot2 with ones)
      unsigned q[8];
      #pragma unroll
      for (int g = 0; g < 8; ++g) {
        float w0 = __builtin_amdgcn_exp2f(S[2 * g]);
        float w1 = __builtin_amdgcn_exp2f(S[2 * g + 1]);
        unsigned u = pk2bf(w0, w1);
        q[g] = u;
        if (s & 1) cs1 = csum2(u, cs1); else cs0 = csum2(u, cs0);
      }

      // σ-permute: q[] is already A-operand ordered — no cross-lane moves
      union { unsigned d[4]; short8 s8; } a20, a21;
      a20.d[0] = q[0]; a20.d[1] = q[1]; a20.d[2] = q[2]; a20.d[3] = q[3];
      a21.d[0] = q[4]; a21.d[1] = q[5]; a21.d[2] = q[6]; a21.d[3] = q[7];

      // B-frags (X): sXB[buf][(dt*32+c)][chunk]
      short8 b20[2], b21[2];
      #pragma unroll
      for (int dt = 0; dt < 2; ++dt) {
        b20[dt] = *(const short8*)(bfb0[s] + buf * 8192 + dt * 4096);
        b21[dt] = *(const short8*)(bfb1[s] + buf * 8192 + dt * 4096);
      }
      #pragma unroll
      for (int dt = 0; dt < 2; ++dt)
        acc[dt] = __builtin_amdgcn_mfma_f32_32x32x16_bf16(a20.s8, b20[dt], acc[dt], 0, 0, 0);
      #pragma unroll
      for (int dt = 0; dt < 2; ++dt)
        acc[dt] = __builtin_amdgcn_mfma_f32_32x32x16_bf16(a21.s8, b21[dt], acc[dt], 0, 0, 0);
    }

    __syncthreads();   // all waves done with buf; prefetch DMA drained
  }

  float cs = cs0 + cs1;

  // -------- epilogue: wave-disjoint outputs, direct global writes ----------
  union { float f; int i; } cu; cu.f = cs;
  cu.i = __builtin_amdgcn_ds_bpermute(bpaddr, cu.i);
  float cst = cs + cu.f;                     // both h-halves hold the total
  if (h == 0) pcs[(size_t)bx * 128 + wave * 32 + c] = cst;

  float* pw = pacc + (size_t)bx * (MTQ * 64);
  #pragma unroll
  for (int dt = 0; dt < 2; ++dt)
    #pragma unroll
    for (int p = 0; p < 16; ++p) {
      int m = wave * 32 + (p & 3) + 8 * (p >> 2) + 4 * h;
      pw[m * 64 + dt * 32 + c] = acc[dt][p];
    }
}

// ---------------------------------------------------------------------------
// combine: sum KS partials, normalize, blend with x_cur (= out slice t),
// write out slice t+1 + next iteration's Xbf / XT (bf16).
// 576 blocks, each owns a 32-query x 64-d slab of a 128-q flash block.
// ---------------------------------------------------------------------------
__global__ void combine_kernel(const float* __restrict__ pacc,
                               const float* __restrict__ pcs,
                               float* __restrict__ out,
                               unsigned short* __restrict__ XT,
                               unsigned short* __restrict__ Xbf, int t)
{
  const int bx  = blockIdx.x;
  const int q32 = bx % 288, b = bx / 288;
  const int m0  = q32 * 32;
  const int base = (b * MBF + (q32 >> 2)) * KS;  // flash block row (128 q)
  const int poff = (q32 & 3) * 2048;             // float offset into 128x64 blk
  const int coff = (q32 & 3) * 32;
  const int tid = threadIdx.x;
  __shared__ float accs[32 * 65];
  __shared__ float cstl[32];

  #pragma unroll
  for (int r = 0; r < 2; ++r) {
    int i4 = r * 256 + tid;                      // float4 idx within 32x64
    float4 s = make_float4(0.f, 0.f, 0.f, 0.f);
    #pragma unroll
    for (int k = 0; k < KS; ++k) {
      const float4* p = (const float4*)(pacc + (size_t)(base + k) * 8192 + poff);
      float4 v = p[i4];
      s.x += v.x; s.y += v.y; s.z += v.z; s.w += v.w;
    }
    int m = i4 >> 4, d0 = (i4 & 15) * 4;
    accs[m * 65 + d0 + 0] = s.x;
    accs[m * 65 + d0 + 1] = s.y;
    accs[m * 65 + d0 + 2] = s.z;
    accs[m * 65 + d0 + 3] = s.w;
  }
  if (tid < 32) {
    float cv = 0.f;
    #pragma unroll
    for (int k = 0; k < KS; ++k) cv += pcs[(size_t)(base + k) * 128 + coff + tid];
    cstl[tid] = cv;
  }
  __syncthreads();

  #pragma unroll
  for (int r = 0; r < 4; ++r) {
    int idx = r * 256 + tid;                    // 0..1023
    int ml = (idx & 15) * 2, d = idx >> 4;      // m fastest -> coalesced n
    float a0 = accs[ml * 65 + d], a1 = accs[(ml + 1) * 65 + d];
    size_t obase = (((size_t)b * 5 + t) * 64 + d) * N_ + m0 + ml;
    float2 xc = *(const float2*)(out + obase);
    float v0 = STEP * (a0 / cstl[ml])     + (1.f - STEP) * xc.x;
    float v1 = STEP * (a1 / cstl[ml + 1]) + (1.f - STEP) * xc.y;
    *(float2*)(out + obase + (size_t)64 * N_) = make_float2(v0, v1);  // slice t+1
    *(unsigned*)(Xbf + ((size_t)b * 64 + d) * N_ + m0 + ml) = pk2bf(v0, v1);
    accs[ml * 65 + d] = v0; accs[(ml + 1) * 65 + d] = v1;  // for transpose
  }
  __syncthreads();

  #pragma unroll
  for (int r = 0; r < 4; ++r) {
    int idx = r * 256 + tid;
    int m = idx >> 5, d = (idx & 31) * 2;       // d fastest -> coalesced XT row
    *(unsigned*)(XT + ((size_t)b * N_ + m0 + m) * 64 + d)
        = pk2bf(accs[m * 65 + d], accs[m * 65 + d + 1]);
  }
}

// ---------------------------------------------------------------------------
extern "C" void kernel_launch(void* const* d_in, const int* in_sizes, int n_in,
                              void* d_out, int out_size, void* d_ws, size_t ws_size,
                              hipStream_t stream)
{
  (void)in_sizes; (void)n_in; (void)out_size; (void)ws_size;
  const float* xin = (const float*)d_in[0];
  float* out = (float*)d_out;
  char* ws = (char*)d_ws;

  // workspace layout (19,095,552 B used — under the R1-R8 23.9 MB footprint):
  unsigned short* XT  = (unsigned short*)(ws);             //  2,359,296 B
  unsigned short* Xbf = (unsigned short*)(ws +  2359296);  //  2,359,296 B
  float*          pacc = (float*)(ws +  4718592);          // 14,155,776 B (432*8192*4)
  float*          pcs  = (float*)(ws + 18874368);          //    221,184 B (432*128*4)

  prep_kernel<<<B_ * PB, 256, 0, stream>>>(xin, out, XT, Xbf);
  for (int t = 0; t < ITERS; ++t) {
    flash_kernel<<<NWG, 256, 0, stream>>>(XT, Xbf, pacc, pcs);
    combine_kernel<<<CGRID, 256, 0, stream>>>(pacc, pcs, out, XT, Xbf, t);
  }
}

// Round 13
// 340.038 us; speedup vs baseline: 1.1123x; 1.0084x over previous
//
#include <hip/hip_runtime.h>
#include <hip/hip_bf16.h>

// Problem constants (B=2, D=64, H=W=96)
constexpr int B_    = 2;
constexpr int N_    = 9216;      // 96*96
constexpr int ITERS = 4;

constexpr int MTQ     = 128;          // queries per workgroup (m-split: 32/wave)
constexpr int MBF     = N_ / MTQ;     // 72 m-blocks
constexpr int KS      = 3;            // key-split factor
constexpr int KEYS_WG = N_ / KS;      // 3072 keys per workgroup
constexpr int KT      = 128;          // keys per staged tile
constexpr int KTILES  = KEYS_WG / KT; // 24 tiles -> 24 barriers
constexpr int NWG     = B_ * MBF * KS;// 432 flash workgroups — all <= cap 2/CU
constexpr int PB      = 144;          // prep n-blocks of 64
constexpr int CGRID   = B_ * (N_ / 32) * 2; // 1152 combine workgroups (d-split)

constexpr float STEP = 0.5f;
constexpr float C2   = 0.43280851226668905f;  // KBW * log2(e)

using short8   = __attribute__((ext_vector_type(8))) short;
using float16v = __attribute__((ext_vector_type(16))) float;
typedef __attribute__((ext_vector_type(2))) __bf16 bf16x2;

__device__ __forceinline__ unsigned short f2bf(float f) {
  union { float f; unsigned u; } v; v.f = f;
  unsigned u = v.u;
  unsigned r = (u + 0x7fffu + ((u >> 16) & 1u)) >> 16;   // RNE
  return (unsigned short)r;
}

#if __has_builtin(__builtin_amdgcn_cvt_pk_bf16_f32)
__device__ __forceinline__ unsigned pk2bf(float a, float b) {
  bf16x2 r = __builtin_amdgcn_cvt_pk_bf16_f32(a, b);   // low <- a, high <- b, RNE
  union { bf16x2 h; unsigned u; } v; v.h = r; return v.u;
}
#else
__device__ __forceinline__ unsigned pk2bf(float a, float b) {
  return (unsigned)f2bf(a) | ((unsigned)f2bf(b) << 16);
}
#endif

// cs += lo(u) + hi(u) where u is a packed bf16 pair — 1 instr via dot2.
__device__ __forceinline__ float csum2(unsigned u, float cs) {
#if __has_builtin(__builtin_amdgcn_fdot2_f32_bf16)
  union { unsigned x; bf16x2 h; } a, o;
  a.x = u; o.x = 0x3f803f80u;                          // (1.0, 1.0) bf16
  return __builtin_amdgcn_fdot2_f32_bf16(a.h, o.h, cs, false);
#else
  union { unsigned u; float f; } lo, hi;
  lo.u = u << 16; hi.u = u & 0xffff0000u;
  return cs + lo.f + hi.f;
#endif
}

// Async global->LDS DMA, 16 B/lane; lds_base wave-uniform, lane i -> base+16i.
__device__ __forceinline__ void dma16(const unsigned short* g,
                                      unsigned short* lds_base, int lane) {
#if __has_builtin(__builtin_amdgcn_global_load_lds)
  __builtin_amdgcn_global_load_lds(
      (const __attribute__((address_space(1))) unsigned int*)g,
      (__attribute__((address_space(3))) unsigned int*)lds_base, 16, 0, 0);
#else
  *(int4*)((char*)lds_base + lane * 16) = *(const int4*)g;
#endif
}

// ---------------------------------------------------------------------------
// prep: x_in (fp32 [b][d][n]) -> out slice 0 (copy), Xbf bf16 [b][d][n],
//       XT bf16 [b][n][d] (LDS transpose)
// ---------------------------------------------------------------------------
__global__ void prep_kernel(const float* __restrict__ xin, float* __restrict__ out,
                            unsigned short* __restrict__ XT,
                            unsigned short* __restrict__ Xbf)
{
  const int bx = blockIdx.x;
  const int nb = bx % PB, b = bx / PB;
  const int n0 = nb * 64;
  const int tid = threadIdx.x;
  __shared__ float tile[64 * 65];

  #pragma unroll
  for (int r = 0; r < 16; ++r) {
    int idx = r * 256 + tid;
    int d = idx >> 6, j = idx & 63;
    float v = xin[((size_t)b * 64 + d) * N_ + n0 + j];
    out[(((size_t)b * 5 + 0) * 64 + d) * N_ + n0 + j] = v;
    Xbf[((size_t)b * 64 + d) * N_ + n0 + j] = f2bf(v);
    tile[d * 65 + j] = v;
  }
  __syncthreads();
  #pragma unroll
  for (int r = 0; r < 16; ++r) {
    int idx = r * 256 + tid;
    int nl = idx >> 6, d = idx & 63;
    XT[((size_t)b * N_ + n0 + nl) * 64 + d] = f2bf(tile[d * 65 + nl]);
  }
}

// ---------------------------------------------------------------------------
// flash (R17 config, FROZEN — measured 73.3 µs, best of 12 structural
// variants). Final model: wall = 162 units/SIMD x ~1.1k cy/unit, invariant
// across staging depth / vmcnt counting / setprio / W-carry / occupancy x1.7
// / LDS-read halving / barrier count. Per-unit pipe-sum is ~500 cy; the
// residual ~600 cy/unit saturates a resource not visible in the SQ/TCC
// counter set. KT=128/KS=3: 24 barriers, 432 blocks (max 2/CU = cap, single
// round), the best-measured point of the family.
// σ-trick (R6): af reads key row σ(c)=c with bits 2<->3 swapped -> W lands
// A-operand-ordered, no cross-lane moves. Queries pre-scaled by C2 ->
// w = exp2(S). Colsum via bf16 dot2 on ROUNDED weights.
// ---------------------------------------------------------------------------
__global__ void __launch_bounds__(256, 2) flash_kernel(
    const unsigned short* __restrict__ XT,
    const unsigned short* __restrict__ Xbf,
    float* __restrict__ pacc, float* __restrict__ pcs)
{
  const int bx   = blockIdx.x;
  const int ks   = bx % KS;
  const int mb   = (bx / KS) % MBF;
  const int b    = bx / (MBF * KS);
  const int tid  = threadIdx.x;
  const int wave = tid >> 6, lane = tid & 63;
  const int c = lane & 31, h = lane >> 5;
  const int cp = (c & 0x13) | ((c & 4) << 1) | ((c & 8) >> 1);  // swap bits 2,3
  const int m0 = mb * MTQ;
  const int bpaddr = (lane ^ 32) << 2;      // ds_bpermute byte index (epilogue)

  const unsigned short* XTb = XT  + (size_t)b * N_ * 64;
  const unsigned short* Xb  = Xbf + (size_t)b * 64 * N_;

  __shared__ __align__(16) unsigned short sXT[2][KT * 64];   // [key][d] 16KiB x2
  __shared__ __align__(16) unsigned short sXB[2][64 * KT];   // [d][n]   16KiB x2

  // sXT: 8 rows x 8 chunks per dma16; row&7 == rr -> lane-constant swizzle.
  const int rr  = lane >> 3, sc = lane & 7;
  const int gcT = sc ^ rr;
  // sXB: 4 rows x 16 chunks per dma16; row&7 = (j&1)*4 + rr4 -> two swizzles.
  const int rr4 = lane >> 4, sc16 = lane & 15;
  const int gcB0 = sc16 ^ rr4;                  // j even
  const int gcB1 = sc16 ^ (4 + rr4);            // j odd

  const int n0g0 = ks * KEYS_WG;

  const unsigned short* xtp  = XTb + (size_t)(n0g0 + wave * 32 + rr) * 64 + gcT * 8;
  const unsigned short* xbpA = Xb  + (size_t)(wave * 16 + rr4) * N_ + n0g0 + gcB0 * 8;
  const unsigned short* xbpB = Xb  + (size_t)(wave * 16 + rr4) * N_ + n0g0 + gcB1 * 8;

  auto stage = [&](int buf, const unsigned short* xt_,
                   const unsigned short* xbA_, const unsigned short* xbB_) {
    unsigned short* lt = &sXT[buf][wave * 32 * 64];    // 32 key rows / wave
    unsigned short* lb = &sXB[buf][wave * 16 * 128];   // 16 d rows / wave
    dma16(xt_,        lt,        lane);
    dma16(xt_ +  512, lt +  512, lane);
    dma16(xt_ + 1024, lt + 1024, lane);
    dma16(xt_ + 1536, lt + 1536, lane);
    dma16(xbA_,                    lb,        lane);
    dma16(xbB_ + (size_t) 4 * N_,  lb +  512, lane);
    dma16(xbA_ + (size_t) 8 * N_,  lb + 1024, lane);
    dma16(xbB_ + (size_t)12 * N_,  lb + 1536, lane);
  };

  stage(0, xtp, xbpA, xbpB);                 // prologue DMA flies under qf setup
  xtp += KT * 64; xbpA += KT; xbpB += KT;

  // wave's resident query fragments (B-operand), pre-scaled by C2
  short8 qf[4];
  #pragma unroll
  for (int k = 0; k < 4; ++k) {
    short8 raw = *(const short8*)(XTb +
        (size_t)(m0 + wave * 32 + c) * 64 + k * 16 + h * 8);
    unsigned o[4];
    const unsigned* rw = (const unsigned*)&raw;
    #pragma unroll
    for (int p4 = 0; p4 < 4; ++p4) {
      union { unsigned u; float f; } lo, hi;
      lo.u = rw[p4] << 16; hi.u = rw[p4] & 0xffff0000u;
      o[p4] = pk2bf(lo.f * C2, hi.f * C2);
    }
    qf[k] = *(const short8*)o;
  }

  const int e = cp & 7;
  const unsigned short* afb[4];
  #pragma unroll
  for (int k = 0; k < 4; ++k)
    afb[k] = &sXT[0][cp * 64 + ((2 * k + h) ^ e) * 8];
  const int ec = c & 7;
  const unsigned short* bfb0[4], * bfb1[4];   // [s], k2=0 / k2=1
  #pragma unroll
  for (int s = 0; s < 4; ++s) {
    bfb0[s] = &sXB[0][c * 128 + ((4 * s +     h) ^ ec) * 8];
    bfb1[s] = &sXB[0][c * 128 + ((4 * s + 2 + h) ^ ec) * 8];
  }

  float16v zv;
  #pragma unroll
  for (int p = 0; p < 16; ++p) zv[p] = 0.f;
  float16v acc[2];
  acc[0] = zv; acc[1] = zv;
  float cs0 = 0.f, cs1 = 0.f;

  __syncthreads();               // buf0 ready (drains prologue DMA + qf loads)

  #pragma unroll 2
  for (int t = 0; t < KTILES; ++t) {
    const int buf = t & 1;       // constexpr after unroll-2
    if (t + 1 < KTILES) {        // prefetch next tile FIRST (overlaps compute)
      stage(buf ^ 1, xtp, xbpA, xbpB);
      xtp += KT * 64; xbpA += KT; xbpB += KT;
    }

    #pragma unroll
    for (int s = 0; s < 4; ++s) {           // 4 key subtiles of 32
      short8 af[4];
      #pragma unroll
      for (int k = 0; k < 4; ++k)
        af[k] = *(const short8*)(afb[k] + buf * 8192 + s * 2048);

      float16v S = zv;
      #pragma unroll
      for (int k = 0; k < 4; ++k)
        S = __builtin_amdgcn_mfma_f32_32x32x16_bf16(af[k], qf[k], S, 0, 0, 0);

      unsigned q[8];
      #pragma unroll
      for (int g = 0; g < 8; ++g) {
        float w0 = __builtin_amdgcn_exp2f(S[2 * g]);
        float w1 = __builtin_amdgcn_exp2f(S[2 * g + 1]);
        unsigned u = pk2bf(w0, w1);
        q[g] = u;
        if (s & 1) cs1 = csum2(u, cs1); else cs0 = csum2(u, cs0);
      }

      union { unsigned d[4]; short8 s8; } a20, a21;
      a20.d[0] = q[0]; a20.d[1] = q[1]; a20.d[2] = q[2]; a20.d[3] = q[3];
      a21.d[0] = q[4]; a21.d[1] = q[5]; a21.d[2] = q[6]; a21.d[3] = q[7];

      short8 b20[2], b21[2];
      #pragma unroll
      for (int dt = 0; dt < 2; ++dt) {
        b20[dt] = *(const short8*)(bfb0[s] + buf * 8192 + dt * 4096);
        b21[dt] = *(const short8*)(bfb1[s] + buf * 8192 + dt * 4096);
      }
      #pragma unroll
      for (int dt = 0; dt < 2; ++dt)
        acc[dt] = __builtin_amdgcn_mfma_f32_32x32x16_bf16(a20.s8, b20[dt], acc[dt], 0, 0, 0);
      #pragma unroll
      for (int dt = 0; dt < 2; ++dt)
        acc[dt] = __builtin_amdgcn_mfma_f32_32x32x16_bf16(a21.s8, b21[dt], acc[dt], 0, 0, 0);
    }

    __syncthreads();   // all waves done with buf; prefetch DMA drained
  }

  float cs = cs0 + cs1;

  // -------- epilogue: wave-disjoint outputs, direct global writes ----------
  union { float f; int i; } cu; cu.f = cs;
  cu.i = __builtin_amdgcn_ds_bpermute(bpaddr, cu.i);
  float cst = cs + cu.f;                     // both h-halves hold the total
  if (h == 0) pcs[(size_t)bx * 128 + wave * 32 + c] = cst;

  float* pw = pacc + (size_t)bx * (MTQ * 64);
  #pragma unroll
  for (int dt = 0; dt < 2; ++dt)
    #pragma unroll
    for (int p = 0; p < 16; ++p) {
      int m = wave * 32 + (p & 3) + 8 * (p >> 2) + 4 * h;
      pw[m * 64 + dt * 32 + c] = acc[dt][p];
    }
}

// ---------------------------------------------------------------------------
// combine v2 (R18): d-split to 1152 blocks (32q x 32d slabs) for 2x TLP at
// UNCHANGED coalescing width (out rows stay 128 B); xc float2s prefetched
// into registers BEFORE the barrier (removes the serial post-barrier global
// read); accs restrided to [32][33] scalar (max 2-way bank aliasing on all
// three passes — stride-40 float4 variant had an 8-way on pass 2).
// Old combine measured ~10.4 µs at 3.2 TB/s effective (TLP-limited, 2.25
// waves/SIMD); predicted ~6-7 µs at 4.5 waves/SIMD.
// ---------------------------------------------------------------------------
__global__ void combine_kernel(const float* __restrict__ pacc,
                               const float* __restrict__ pcs,
                               float* __restrict__ out,
                               unsigned short* __restrict__ XT,
                               unsigned short* __restrict__ Xbf, int t)
{
  const int bx  = blockIdx.x;
  const int dh  = bx & 1;                        // d-half: 0 -> d 0..31, 1 -> 32..63
  const int q32 = (bx >> 1) % 288, b = bx / 576;
  const int m0  = q32 * 32;
  const int fb  = q32 >> 2, sub = q32 & 3;       // flash 128-q block / 32-q slab
  const int base = (b * MBF + fb) * KS;
  const int tid = threadIdx.x;
  __shared__ float accs[32 * 33];
  __shared__ float cstl[32];

  // ---- prefetch xc (out slice t) for both pass-2 rounds: no LDS dep -------
  float2 xc[2];
  int   dl2[2], ml2[2];
  size_t ob2[2];
  #pragma unroll
  for (int r = 0; r < 2; ++r) {
    int idx = r * 256 + tid;                     // 0..511
    int ml = (idx & 15) * 2, dl = idx >> 4;      // ml 0..30, dl 0..31
    int d  = dh * 32 + dl;
    size_t obase = (((size_t)b * 5 + t) * 64 + d) * N_ + m0 + ml;
    xc[r] = *(const float2*)(out + obase);
    ml2[r] = ml; dl2[r] = dl; ob2[r] = obase;
  }

  // ---- pass 1: sum KS pacc partials for this 32q x 32d slab ---------------
  {
    int ml = tid >> 3, f4 = tid & 7;             // 32 rows x 8 float4
    size_t off = (size_t)(sub * 32 + ml) * 64 + dh * 32 + f4 * 4;
    float4 s = make_float4(0.f, 0.f, 0.f, 0.f);
    #pragma unroll
    for (int k = 0; k < KS; ++k) {
      float4 v = *(const float4*)(pacc + (size_t)(base + k) * 8192 + off);
      s.x += v.x; s.y += v.y; s.z += v.z; s.w += v.w;
    }
    float* a = &accs[ml * 33 + f4 * 4];
    a[0] = s.x; a[1] = s.y; a[2] = s.z; a[3] = s.w;
  }
  if (tid < 32) {
    float cv = 0.f;
    #pragma unroll
    for (int k = 0; k < KS; ++k) cv += pcs[(size_t)(base + k) * 128 + sub * 32 + tid];
    cstl[tid] = cv;
  }
  __syncthreads();

  // ---- pass 2: normalize, blend, write out slice t+1 + Xbf ----------------
  #pragma unroll
  for (int r = 0; r < 2; ++r) {
    int ml = ml2[r], dl = dl2[r];
    float a0 = accs[ml * 33 + dl], a1 = accs[(ml + 1) * 33 + dl];
    float v0 = STEP * (a0 / cstl[ml])     + (1.f - STEP) * xc[r].x;
    float v1 = STEP * (a1 / cstl[ml + 1]) + (1.f - STEP) * xc[r].y;
    *(float2*)(out + ob2[r] + (size_t)64 * N_) = make_float2(v0, v1);  // slice t+1
    int d = dh * 32 + dl;
    *(unsigned*)(Xbf + ((size_t)b * 64 + d) * N_ + m0 + ml) = pk2bf(v0, v1);
    accs[ml * 33 + dl] = v0; accs[(ml + 1) * 33 + dl] = v1;  // for transpose
  }
  __syncthreads();

  // ---- pass 3: transposed XT write (d fastest -> coalesced XT rows) -------
  #pragma unroll
  for (int r = 0; r < 2; ++r) {
    int idx = r * 256 + tid;                     // 0..511
    int m = idx >> 4, dl = (idx & 15) * 2;       // m 0..31, dl 0..30
    *(unsigned*)(XT + ((size_t)b * N_ + m0 + m) * 64 + dh * 32 + dl)
        = pk2bf(accs[m * 33 + dl], accs[m * 33 + dl + 1]);
  }
}

// ---------------------------------------------------------------------------
extern "C" void kernel_launch(void* const* d_in, const int* in_sizes, int n_in,
                              void* d_out, int out_size, void* d_ws, size_t ws_size,
                              hipStream_t stream)
{
  (void)in_sizes; (void)n_in; (void)out_size; (void)ws_size;
  const float* xin = (const float*)d_in[0];
  float* out = (float*)d_out;
  char* ws = (char*)d_ws;

  // workspace layout (19,095,552 B used):
  unsigned short* XT  = (unsigned short*)(ws);             //  2,359,296 B
  unsigned short* Xbf = (unsigned short*)(ws +  2359296);  //  2,359,296 B
  float*          pacc = (float*)(ws +  4718592);          // 14,155,776 B (432*8192*4)
  float*          pcs  = (float*)(ws + 18874368);          //    221,184 B (432*128*4)

  prep_kernel<<<B_ * PB, 256, 0, stream>>>(xin, out, XT, Xbf);
  for (int t = 0; t < ITERS; ++t) {
    flash_kernel<<<NWG, 256, 0, stream>>>(XT, Xbf, pacc, pcs);
    combine_kernel<<<CGRID, 256, 0, stream>>>(pacc, pcs, out, XT, Xbf, t);
  }
}

// Round 14
// 336.077 us; speedup vs baseline: 1.1254x; 1.0118x over previous
//
#include <hip/hip_runtime.h>
#include <hip/hip_bf16.h>

// Problem constants (B=2, D=64, H=W=96)
constexpr int B_    = 2;
constexpr int N_    = 9216;      // 96*96
constexpr int ITERS = 4;

constexpr int MTQ     = 128;          // queries per workgroup (m-split: 32/wave)
constexpr int MBF     = N_ / MTQ;     // 72 m-blocks
constexpr int KS      = 3;            // key-split factor
constexpr int KEYS_WG = N_ / KS;      // 3072 keys per workgroup
constexpr int KT      = 128;          // keys per staged tile
constexpr int KTILES  = KEYS_WG / KT; // 24 tiles -> 24 barriers
constexpr int NWG     = B_ * MBF * KS;// 432 flash workgroups — all <= cap 2/CU
constexpr int PB2     = 288;          // prep n-blocks of 32 (R19: 2x TLP)
constexpr int CGRID   = B_ * (N_ / 32) * 2; // 1152 combine workgroups (d-split)

constexpr float STEP = 0.5f;
constexpr float C2   = 0.43280851226668905f;  // KBW * log2(e)

using short8   = __attribute__((ext_vector_type(8))) short;
using float16v = __attribute__((ext_vector_type(16))) float;
typedef __attribute__((ext_vector_type(2))) __bf16 bf16x2;

__device__ __forceinline__ unsigned short f2bf(float f) {
  union { float f; unsigned u; } v; v.f = f;
  unsigned u = v.u;
  unsigned r = (u + 0x7fffu + ((u >> 16) & 1u)) >> 16;   // RNE
  return (unsigned short)r;
}

#if __has_builtin(__builtin_amdgcn_cvt_pk_bf16_f32)
__device__ __forceinline__ unsigned pk2bf(float a, float b) {
  bf16x2 r = __builtin_amdgcn_cvt_pk_bf16_f32(a, b);   // low <- a, high <- b, RNE
  union { bf16x2 h; unsigned u; } v; v.h = r; return v.u;
}
#else
__device__ __forceinline__ unsigned pk2bf(float a, float b) {
  return (unsigned)f2bf(a) | ((unsigned)f2bf(b) << 16);
}
#endif

// cs += lo(u) + hi(u) where u is a packed bf16 pair — 1 instr via dot2.
__device__ __forceinline__ float csum2(unsigned u, float cs) {
#if __has_builtin(__builtin_amdgcn_fdot2_f32_bf16)
  union { unsigned x; bf16x2 h; } a, o;
  a.x = u; o.x = 0x3f803f80u;                          // (1.0, 1.0) bf16
  return __builtin_amdgcn_fdot2_f32_bf16(a.h, o.h, cs, false);
#else
  union { unsigned u; float f; } lo, hi;
  lo.u = u << 16; hi.u = u & 0xffff0000u;
  return cs + lo.f + hi.f;
#endif
}

// Async global->LDS DMA, 16 B/lane; lds_base wave-uniform, lane i -> base+16i.
__device__ __forceinline__ void dma16(const unsigned short* g,
                                      unsigned short* lds_base, int lane) {
#if __has_builtin(__builtin_amdgcn_global_load_lds)
  __builtin_amdgcn_global_load_lds(
      (const __attribute__((address_space(1))) unsigned int*)g,
      (__attribute__((address_space(3))) unsigned int*)lds_base, 16, 0, 0);
#else
  *(int4*)((char*)lds_base + lane * 16) = *(const int4*)g;
#endif
}

// ---------------------------------------------------------------------------
// prep v2 (R19): x_in (fp32 [b][d][n]) -> out slice 0 (copy), Xbf bf16
// [b][d][n], XT bf16 [b][n][d]. 576 blocks (32 n-cols x 64 d each) for
// 2.25 waves/SIMD (old 288-block version ran at 1.1 waves/SIMD — same TLP
// starvation combine v1 had); float2 loads; PACKED 32-bit bf16 stores for
// Xbf and XT (halves store count); LDS [64][33] (2-way bank alias max on
// both passes — free per m136).
// ---------------------------------------------------------------------------
__global__ void prep_kernel(const float* __restrict__ xin, float* __restrict__ out,
                            unsigned short* __restrict__ XT,
                            unsigned short* __restrict__ Xbf)
{
  const int bx = blockIdx.x;
  const int nb = bx % PB2, b = bx / PB2;
  const int n0 = nb * 32;
  const int tid = threadIdx.x;
  __shared__ float tile[64 * 33];

  // pass 1: read 64d x 32n slab as float2; write out slice0 + packed Xbf
  #pragma unroll
  for (int r = 0; r < 4; ++r) {
    int idx = r * 256 + tid;                 // 0..1023 = 64 d x 16 j-pairs
    int d = idx >> 4, j2 = (idx & 15) * 2;
    size_t gsrc = ((size_t)b * 64 + d) * N_ + n0 + j2;
    float2 v = *(const float2*)(xin + gsrc);
    *(float2*)(out + (((size_t)b * 5 + 0) * 64 + d) * N_ + n0 + j2) = v;
    *(unsigned*)(Xbf + gsrc) = pk2bf(v.x, v.y);
    tile[d * 33 + j2]     = v.x;
    tile[d * 33 + j2 + 1] = v.y;
  }
  __syncthreads();

  // pass 2: transposed packed XT write (d fastest -> coalesced XT rows)
  #pragma unroll
  for (int r = 0; r < 4; ++r) {
    int idx = r * 256 + tid;                 // 0..1023 = 32 n x 32 d-pairs
    int nl = idx >> 5, d2 = (idx & 31) * 2;
    *(unsigned*)(XT + ((size_t)b * N_ + n0 + nl) * 64 + d2)
        = pk2bf(tile[d2 * 33 + nl], tile[(d2 + 1) * 33 + nl]);
  }
}

// ---------------------------------------------------------------------------
// flash (R17 config, FROZEN — measured 73.3-75.0 µs, best of 13 structural
// variants). Final model: wall = 162 units/SIMD x ~1.1k cy/unit, invariant
// across staging depth / vmcnt counting / setprio / W-carry / occupancy x1.7
// / LDS-read halving / barrier count. Per-unit pipe-sum is ~500 cy; the
// residual saturates a resource not visible in the SQ/TCC counter set.
// KT=128/KS=3: 24 barriers, 432 blocks (max 2/CU = cap, single round).
// σ-trick (R6): af reads key row σ(c)=c with bits 2<->3 swapped -> W lands
// A-operand-ordered, no cross-lane moves. Queries pre-scaled by C2 ->
// w = exp2(S). Colsum via bf16 dot2 on ROUNDED weights.
// ---------------------------------------------------------------------------
__global__ void __launch_bounds__(256, 2) flash_kernel(
    const unsigned short* __restrict__ XT,
    const unsigned short* __restrict__ Xbf,
    float* __restrict__ pacc, float* __restrict__ pcs)
{
  const int bx   = blockIdx.x;
  const int ks   = bx % KS;
  const int mb   = (bx / KS) % MBF;
  const int b    = bx / (MBF * KS);
  const int tid  = threadIdx.x;
  const int wave = tid >> 6, lane = tid & 63;
  const int c = lane & 31, h = lane >> 5;
  const int cp = (c & 0x13) | ((c & 4) << 1) | ((c & 8) >> 1);  // swap bits 2,3
  const int m0 = mb * MTQ;
  const int bpaddr = (lane ^ 32) << 2;      // ds_bpermute byte index (epilogue)

  const unsigned short* XTb = XT  + (size_t)b * N_ * 64;
  const unsigned short* Xb  = Xbf + (size_t)b * 64 * N_;

  __shared__ __align__(16) unsigned short sXT[2][KT * 64];   // [key][d] 16KiB x2
  __shared__ __align__(16) unsigned short sXB[2][64 * KT];   // [d][n]   16KiB x2

  // sXT: 8 rows x 8 chunks per dma16; row&7 == rr -> lane-constant swizzle.
  const int rr  = lane >> 3, sc = lane & 7;
  const int gcT = sc ^ rr;
  // sXB: 4 rows x 16 chunks per dma16; row&7 = (j&1)*4 + rr4 -> two swizzles.
  const int rr4 = lane >> 4, sc16 = lane & 15;
  const int gcB0 = sc16 ^ rr4;                  // j even
  const int gcB1 = sc16 ^ (4 + rr4);            // j odd

  const int n0g0 = ks * KEYS_WG;

  const unsigned short* xtp  = XTb + (size_t)(n0g0 + wave * 32 + rr) * 64 + gcT * 8;
  const unsigned short* xbpA = Xb  + (size_t)(wave * 16 + rr4) * N_ + n0g0 + gcB0 * 8;
  const unsigned short* xbpB = Xb  + (size_t)(wave * 16 + rr4) * N_ + n0g0 + gcB1 * 8;

  auto stage = [&](int buf, const unsigned short* xt_,
                   const unsigned short* xbA_, const unsigned short* xbB_) {
    unsigned short* lt = &sXT[buf][wave * 32 * 64];    // 32 key rows / wave
    unsigned short* lb = &sXB[buf][wave * 16 * 128];   // 16 d rows / wave
    dma16(xt_,        lt,        lane);
    dma16(xt_ +  512, lt +  512, lane);
    dma16(xt_ + 1024, lt + 1024, lane);
    dma16(xt_ + 1536, lt + 1536, lane);
    dma16(xbA_,                    lb,        lane);
    dma16(xbB_ + (size_t) 4 * N_,  lb +  512, lane);
    dma16(xbA_ + (size_t) 8 * N_,  lb + 1024, lane);
    dma16(xbB_ + (size_t)12 * N_,  lb + 1536, lane);
  };

  stage(0, xtp, xbpA, xbpB);                 // prologue DMA flies under qf setup
  xtp += KT * 64; xbpA += KT; xbpB += KT;

  // wave's resident query fragments (B-operand), pre-scaled by C2
  short8 qf[4];
  #pragma unroll
  for (int k = 0; k < 4; ++k) {
    short8 raw = *(const short8*)(XTb +
        (size_t)(m0 + wave * 32 + c) * 64 + k * 16 + h * 8);
    unsigned o[4];
    const unsigned* rw = (const unsigned*)&raw;
    #pragma unroll
    for (int p4 = 0; p4 < 4; ++p4) {
      union { unsigned u; float f; } lo, hi;
      lo.u = rw[p4] << 16; hi.u = rw[p4] & 0xffff0000u;
      o[p4] = pk2bf(lo.f * C2, hi.f * C2);
    }
    qf[k] = *(const short8*)o;
  }

  const int e = cp & 7;
  const unsigned short* afb[4];
  #pragma unroll
  for (int k = 0; k < 4; ++k)
    afb[k] = &sXT[0][cp * 64 + ((2 * k + h) ^ e) * 8];
  const int ec = c & 7;
  const unsigned short* bfb0[4], * bfb1[4];   // [s], k2=0 / k2=1
  #pragma unroll
  for (int s = 0; s < 4; ++s) {
    bfb0[s] = &sXB[0][c * 128 + ((4 * s +     h) ^ ec) * 8];
    bfb1[s] = &sXB[0][c * 128 + ((4 * s + 2 + h) ^ ec) * 8];
  }

  float16v zv;
  #pragma unroll
  for (int p = 0; p < 16; ++p) zv[p] = 0.f;
  float16v acc[2];
  acc[0] = zv; acc[1] = zv;
  float cs0 = 0.f, cs1 = 0.f;

  __syncthreads();               // buf0 ready (drains prologue DMA + qf loads)

  #pragma unroll 2
  for (int t = 0; t < KTILES; ++t) {
    const int buf = t & 1;       // constexpr after unroll-2
    if (t + 1 < KTILES) {        // prefetch next tile FIRST (overlaps compute)
      stage(buf ^ 1, xtp, xbpA, xbpB);
      xtp += KT * 64; xbpA += KT; xbpB += KT;
    }

    #pragma unroll
    for (int s = 0; s < 4; ++s) {           // 4 key subtiles of 32
      short8 af[4];
      #pragma unroll
      for (int k = 0; k < 4; ++k)
        af[k] = *(const short8*)(afb[k] + buf * 8192 + s * 2048);

      float16v S = zv;
      #pragma unroll
      for (int k = 0; k < 4; ++k)
        S = __builtin_amdgcn_mfma_f32_32x32x16_bf16(af[k], qf[k], S, 0, 0, 0);

      unsigned q[8];
      #pragma unroll
      for (int g = 0; g < 8; ++g) {
        float w0 = __builtin_amdgcn_exp2f(S[2 * g]);
        float w1 = __builtin_amdgcn_exp2f(S[2 * g + 1]);
        unsigned u = pk2bf(w0, w1);
        q[g] = u;
        if (s & 1) cs1 = csum2(u, cs1); else cs0 = csum2(u, cs0);
      }

      union { unsigned d[4]; short8 s8; } a20, a21;
      a20.d[0] = q[0]; a20.d[1] = q[1]; a20.d[2] = q[2]; a20.d[3] = q[3];
      a21.d[0] = q[4]; a21.d[1] = q[5]; a21.d[2] = q[6]; a21.d[3] = q[7];

      short8 b20[2], b21[2];
      #pragma unroll
      for (int dt = 0; dt < 2; ++dt) {
        b20[dt] = *(const short8*)(bfb0[s] + buf * 8192 + dt * 4096);
        b21[dt] = *(const short8*)(bfb1[s] + buf * 8192 + dt * 4096);
      }
      #pragma unroll
      for (int dt = 0; dt < 2; ++dt)
        acc[dt] = __builtin_amdgcn_mfma_f32_32x32x16_bf16(a20.s8, b20[dt], acc[dt], 0, 0, 0);
      #pragma unroll
      for (int dt = 0; dt < 2; ++dt)
        acc[dt] = __builtin_amdgcn_mfma_f32_32x32x16_bf16(a21.s8, b21[dt], acc[dt], 0, 0, 0);
    }

    __syncthreads();   // all waves done with buf; prefetch DMA drained
  }

  float cs = cs0 + cs1;

  // -------- epilogue: wave-disjoint outputs, direct global writes ----------
  union { float f; int i; } cu; cu.f = cs;
  cu.i = __builtin_amdgcn_ds_bpermute(bpaddr, cu.i);
  float cst = cs + cu.f;                     // both h-halves hold the total
  if (h == 0) pcs[(size_t)bx * 128 + wave * 32 + c] = cst;

  float* pw = pacc + (size_t)bx * (MTQ * 64);
  #pragma unroll
  for (int dt = 0; dt < 2; ++dt)
    #pragma unroll
    for (int p = 0; p < 16; ++p) {
      int m = wave * 32 + (p & 3) + 8 * (p >> 2) + 4 * h;
      pw[m * 64 + dt * 32 + c] = acc[dt][p];
    }
}

// ---------------------------------------------------------------------------
// combine v2 (R18 config, kept): 1152 blocks (32q x 32d slabs), xc prefetch
// before the barrier, accs [32][33]. Measured ~8 µs/iter (near its ~6 µs BW
// floor at this block count).
// ---------------------------------------------------------------------------
__global__ void combine_kernel(const float* __restrict__ pacc,
                               const float* __restrict__ pcs,
                               float* __restrict__ out,
                               unsigned short* __restrict__ XT,
                               unsigned short* __restrict__ Xbf, int t)
{
  const int bx  = blockIdx.x;
  const int dh  = bx & 1;                        // d-half: 0 -> d 0..31, 1 -> 32..63
  const int q32 = (bx >> 1) % 288, b = bx / 576;
  const int m0  = q32 * 32;
  const int fb  = q32 >> 2, sub = q32 & 3;       // flash 128-q block / 32-q slab
  const int base = (b * MBF + fb) * KS;
  const int tid = threadIdx.x;
  __shared__ float accs[32 * 33];
  __shared__ float cstl[32];

  // ---- prefetch xc (out slice t) for both pass-2 rounds: no LDS dep -------
  float2 xc[2];
  int   dl2[2], ml2[2];
  size_t ob2[2];
  #pragma unroll
  for (int r = 0; r < 2; ++r) {
    int idx = r * 256 + tid;                     // 0..511
    int ml = (idx & 15) * 2, dl = idx >> 4;      // ml 0..30, dl 0..31
    int d  = dh * 32 + dl;
    size_t obase = (((size_t)b * 5 + t) * 64 + d) * N_ + m0 + ml;
    xc[r] = *(const float2*)(out + obase);
    ml2[r] = ml; dl2[r] = dl; ob2[r] = obase;
  }

  // ---- pass 1: sum KS pacc partials for this 32q x 32d slab ---------------
  {
    int ml = tid >> 3, f4 = tid & 7;             // 32 rows x 8 float4
    size_t off = (size_t)(sub * 32 + ml) * 64 + dh * 32 + f4 * 4;
    float4 s = make_float4(0.f, 0.f, 0.f, 0.f);
    #pragma unroll
    for (int k = 0; k < KS; ++k) {
      float4 v = *(const float4*)(pacc + (size_t)(base + k) * 8192 + off);
      s.x += v.x; s.y += v.y; s.z += v.z; s.w += v.w;
    }
    float* a = &accs[ml * 33 + f4 * 4];
    a[0] = s.x; a[1] = s.y; a[2] = s.z; a[3] = s.w;
  }
  if (tid < 32) {
    float cv = 0.f;
    #pragma unroll
    for (int k = 0; k < KS; ++k) cv += pcs[(size_t)(base + k) * 128 + sub * 32 + tid];
    cstl[tid] = cv;
  }
  __syncthreads();

  // ---- pass 2: normalize, blend, write out slice t+1 + Xbf ----------------
  #pragma unroll
  for (int r = 0; r < 2; ++r) {
    int ml = ml2[r], dl = dl2[r];
    float a0 = accs[ml * 33 + dl], a1 = accs[(ml + 1) * 33 + dl];
    float v0 = STEP * (a0 / cstl[ml])     + (1.f - STEP) * xc[r].x;
    float v1 = STEP * (a1 / cstl[ml + 1]) + (1.f - STEP) * xc[r].y;
    *(float2*)(out + ob2[r] + (size_t)64 * N_) = make_float2(v0, v1);  // slice t+1
    int d = dh * 32 + dl;
    *(unsigned*)(Xbf + ((size_t)b * 64 + d) * N_ + m0 + ml) = pk2bf(v0, v1);
    accs[ml * 33 + dl] = v0; accs[(ml + 1) * 33 + dl] = v1;  // for transpose
  }
  __syncthreads();

  // ---- pass 3: transposed XT write (d fastest -> coalesced XT rows) -------
  #pragma unroll
  for (int r = 0; r < 2; ++r) {
    int idx = r * 256 + tid;                     // 0..511
    int m = idx >> 4, dl = (idx & 15) * 2;       // m 0..31, dl 0..30
    *(unsigned*)(XT + ((size_t)b * N_ + m0 + m) * 64 + dh * 32 + dl)
        = pk2bf(accs[m * 33 + dl], accs[m * 33 + dl + 1]);
  }
}

// ---------------------------------------------------------------------------
extern "C" void kernel_launch(void* const* d_in, const int* in_sizes, int n_in,
                              void* d_out, int out_size, void* d_ws, size_t ws_size,
                              hipStream_t stream)
{
  (void)in_sizes; (void)n_in; (void)out_size; (void)ws_size;
  const float* xin = (const float*)d_in[0];
  float* out = (float*)d_out;
  char* ws = (char*)d_ws;

  // workspace layout (19,095,552 B used):
  unsigned short* XT  = (unsigned short*)(ws);             //  2,359,296 B
  unsigned short* Xbf = (unsigned short*)(ws +  2359296);  //  2,359,296 B
  float*          pacc = (float*)(ws +  4718592);          // 14,155,776 B (432*8192*4)
  float*          pcs  = (float*)(ws + 18874368);          //    221,184 B (432*128*4)

  prep_kernel<<<B_ * PB2, 256, 0, stream>>>(xin, out, XT, Xbf);
  for (int t = 0; t < ITERS; ++t) {
    flash_kernel<<<NWG, 256, 0, stream>>>(XT, Xbf, pacc, pcs);
    combine_kernel<<<CGRID, 256, 0, stream>>>(pacc, pcs, out, XT, Xbf, t);
  }
}